// Round 1
// baseline (279.007 us; speedup 1.0000x reference)
//
#include <hip/hip_runtime.h>
#include <hip/hip_bf16.h>
#include <stdint.h>

#define M_TOK 32
#define IN_F 4096
#define OUT_F 11008
#define NSPLIT 4
#define KRANGE (IN_F / NSPLIT)   // 1024 per block
#define KC 128                   // k-chunk staged in LDS
#define NTILE 64                 // output features per block
#define LDA 136                  // padded LDS row (bf16 elems): 128 + 8
#define LDB 136

typedef __attribute__((ext_vector_type(8))) short bf16x8;
typedef __attribute__((ext_vector_type(4))) float f32x4;

__device__ inline uint32_t pack_bf16(float a, float b) {
    __hip_bfloat16 ha = __float2bfloat16(a);
    __hip_bfloat16 hb = __float2bfloat16(b);
    uint16_t ua = *(uint16_t*)&ha;
    uint16_t ub = *(uint16_t*)&hb;
    return (uint32_t)ua | ((uint32_t)ub << 16);
}

// out[m][o] = bias[o]   (grid: 43 x 32, block 256 — exact cover of 11008 x 32)
__global__ void init_out_kernel(const float* __restrict__ bias, float* __restrict__ out) {
    int o = blockIdx.x * 256 + threadIdx.x;
    int m = blockIdx.y;
    out[(size_t)m * OUT_F + o] = bias[o];
}

__launch_bounds__(256)
__global__ void qgemm_kernel(const float* __restrict__ x,
                             const int* __restrict__ wq,
                             const float* __restrict__ sz,
                             float* __restrict__ out) {
    __shared__ __align__(16) short A[M_TOK * LDA];   // bf16 bits
    __shared__ __align__(16) short B[NTILE * LDB];

    const int bid = blockIdx.x;
    const int ks = bid & 3;          // k-split index
    const int nb = bid >> 2;         // n-tile index (0..171)
    const int o0 = nb * NTILE;
    const int k0 = ks * KRANGE;

    const int t  = threadIdx.x;
    const int w  = t >> 6;           // wave 0..3 -> n-subtile of 16
    const int l  = t & 63;
    const int lm = l & 15;
    const int lq = l >> 4;

    f32x4 acc0 = {0.f, 0.f, 0.f, 0.f};
    f32x4 acc1 = {0.f, 0.f, 0.f, 0.f};

    for (int ch = 0; ch < KRANGE / KC; ++ch) {
        const int kb = k0 + ch * KC;

        // ---- issue all global loads first (MLP), then transform ----
        // B: 64 rows x 128 k of int32 -> 8 int4 per thread, coalesced 512B/row-half
        int4  qv[8];
        float2 szv[8];
        #pragma unroll
        for (int rep = 0; rep < 8; ++rep) {
            int s   = t + rep * 256;          // 0..2047
            int r   = s >> 5;                 // row 0..63
            int kc4 = (s & 31) << 2;          // 0..124
            int kg  = kb + kc4;
            qv[rep]  = *(const int4*)(wq + (size_t)(o0 + r) * IN_F + kg);
            int g    = kg >> 5;               // 4 consecutive k stay in one group
            szv[rep] = *(const float2*)(sz + ((size_t)g * OUT_F + (o0 + r)) * 2);
        }
        // A: 32 rows x 128 k fp32 (L2-hot, 16 KB) -> bf16
        float4 av[2][2];
        #pragma unroll
        for (int rep = 0; rep < 2; ++rep) {
            int slot = t + rep * 256;         // 0..511
            int am   = slot >> 4;             // row 0..31
            int ak   = (slot & 15) * 8;       // 0..120
            const float* src = x + (size_t)am * IN_F + kb + ak;
            av[rep][0] = *(const float4*)(src);
            av[rep][1] = *(const float4*)(src + 4);
        }

        // ---- dequant + store to LDS ----
        #pragma unroll
        for (int rep = 0; rep < 8; ++rep) {
            int s   = t + rep * 256;
            int r   = s >> 5;
            int kc4 = (s & 31) << 2;
            float sc = szv[rep].x, zp = szv[rep].y;
            float w0 = (float)(qv[rep].x - 8) * sc + zp;
            float w1 = (float)(qv[rep].y - 8) * sc + zp;
            float w2 = (float)(qv[rep].z - 8) * sc + zp;
            float w3 = (float)(qv[rep].w - 8) * sc + zp;
            uint2 p;
            p.x = pack_bf16(w0, w1);
            p.y = pack_bf16(w2, w3);
            *(uint2*)&B[r * LDB + kc4] = p;   // 8B store, aligned
        }
        #pragma unroll
        for (int rep = 0; rep < 2; ++rep) {
            int slot = t + rep * 256;
            int am   = slot >> 4;
            int ak   = (slot & 15) * 8;
            uint4 p;
            p.x = pack_bf16(av[rep][0].x, av[rep][0].y);
            p.y = pack_bf16(av[rep][0].z, av[rep][0].w);
            p.z = pack_bf16(av[rep][1].x, av[rep][1].y);
            p.w = pack_bf16(av[rep][1].z, av[rep][1].w);
            *(uint4*)&A[am * LDA + ak] = p;   // 16B store, aligned (272 = 17*16)
        }
        __syncthreads();

        // ---- MFMA over the chunk: 4 k-steps of 32 ----
        #pragma unroll
        for (int kk = 0; kk < KC / 32; ++kk) {
            bf16x8 af0 = *(const bf16x8*)&A[lm * LDA        + kk * 32 + lq * 8];
            bf16x8 af1 = *(const bf16x8*)&A[(16 + lm) * LDA + kk * 32 + lq * 8];
            bf16x8 bfr = *(const bf16x8*)&B[(w * 16 + lm) * LDB + kk * 32 + lq * 8];
            acc0 = __builtin_amdgcn_mfma_f32_16x16x32_bf16(af0, bfr, acc0, 0, 0, 0);
            acc1 = __builtin_amdgcn_mfma_f32_16x16x32_bf16(af1, bfr, acc1, 0, 0, 0);
        }
        __syncthreads();
    }

    // ---- epilogue: C/D mapping col=lane&15, row=(lane>>4)*4+reg ----
    const int ocol = o0 + w * 16 + lm;
    #pragma unroll
    for (int i = 0; i < 4; ++i) {
        int m0 = lq * 4 + i;
        atomicAdd(&out[(size_t)m0 * OUT_F + ocol], acc0[i]);
        atomicAdd(&out[(size_t)(16 + m0) * OUT_F + ocol], acc1[i]);
    }
}

extern "C" void kernel_launch(void* const* d_in, const int* in_sizes, int n_in,
                              void* d_out, int out_size, void* d_ws, size_t ws_size,
                              hipStream_t stream) {
    const float* x    = (const float*)d_in[0];   // [32, 4096] fp32
    const int*   wq   = (const int*)d_in[1];     // [11008, 4096] int32 (0..15)
    const float* sz   = (const float*)d_in[2];   // [128, 11008, 2] fp32
    const float* bias = (const float*)d_in[3];   // [11008] fp32
    float* out = (float*)d_out;                  // [32, 11008] fp32

    dim3 gi(OUT_F / 256, M_TOK);                 // 43 x 32
    init_out_kernel<<<gi, 256, 0, stream>>>(bias, out);

    dim3 gg((OUT_F / NTILE) * NSPLIT);           // 172 * 4 = 688 blocks
    qgemm_kernel<<<gg, 256, 0, stream>>>(x, wq, sz, out);
}

// Round 2
// 278.493 us; speedup vs baseline: 1.0018x; 1.0018x over previous
//
#include <hip/hip_runtime.h>
#include <hip/hip_bf16.h>
#include <stdint.h>

#define M_TOK 32
#define IN_F 4096
#define OUT_F 11008
#define NSPLIT 8
#define KRANGE (IN_F / NSPLIT)   // 512 k per block

typedef __attribute__((ext_vector_type(8))) short bf16x8;
typedef __attribute__((ext_vector_type(4))) float f32x4;

__device__ inline uint32_t pack_bf16(float a, float b) {
    __hip_bfloat16 ha = __float2bfloat16(a);
    __hip_bfloat16 hb = __float2bfloat16(b);
    uint16_t ua = *(uint16_t*)&ha;
    uint16_t ub = *(uint16_t*)&hb;
    return (uint32_t)ua | ((uint32_t)ub << 16);
}

// out[m][o] = bias[o]   (grid: 43 x 32, block 256 — exact cover of 11008 x 32)
__global__ void init_out_kernel(const float* __restrict__ bias, float* __restrict__ out) {
    int o = blockIdx.x * 256 + threadIdx.x;
    int m = blockIdx.y;
    out[(size_t)m * OUT_F + o] = bias[o];
}

// Register-direct streaming dequant-GEMM. No LDS, no barriers.
// Wave w of block (nb,ks): out rows [nb*64 + w*16, +16), k range [ks*512, +512).
// B-frag (verified R0): lane holds W[n = base + (lane&15)][k = step*32 + (lane>>4)*8 .. +8)
// A-frag:               lane holds x[m = (lane&15) (+16)][same 8 k]
__launch_bounds__(256)
__global__ void qgemm_kernel(const float* __restrict__ x,
                             const int* __restrict__ wq,
                             const float* __restrict__ sz,
                             float* __restrict__ out) {
    const int bid = blockIdx.x;
    const int ks  = bid & (NSPLIT - 1);
    const int nb  = bid >> 3;
    const int t   = threadIdx.x;
    const int wv  = t >> 6;
    const int l   = t & 63;
    const int lm  = l & 15;
    const int lq  = l >> 4;

    const int row = nb * 64 + wv * 16 + lm;   // out-feature row this lane streams
    const int k0  = ks * KRANGE;

    const int*   wp  = wq + (size_t)row * IN_F + k0 + lq * 8;
    const float* xp0 = x + (size_t)lm * IN_F + k0 + lq * 8;
    const float* xp1 = xp0 + (size_t)16 * IN_F;
    const float* szp = sz + ((size_t)(k0 >> 5) * OUT_F + row) * 2;

    f32x4 acc0 = {0.f, 0.f, 0.f, 0.f};
    f32x4 acc1 = {0.f, 0.f, 0.f, 0.f};

    #pragma unroll 4
    for (int s = 0; s < KRANGE / 32; ++s) {
        int4   q0 = *(const int4*)(wp);
        int4   q1 = *(const int4*)(wp + 4);
        float2 sv = *(const float2*)(szp);
        float4 xa = *(const float4*)(xp0);
        float4 xb = *(const float4*)(xp0 + 4);
        float4 xc = *(const float4*)(xp1);
        float4 xd = *(const float4*)(xp1 + 4);
        wp  += 32;
        xp0 += 32;
        xp1 += 32;
        szp += (size_t)OUT_F * 2;

        const float sc = sv.x;
        const float zp = sv.y - 8.0f * sv.x;   // fold the -8 midpoint into zero

        union { bf16x8 v; uint32_t u[4]; } bf, a0, a1;
        bf.u[0] = pack_bf16((float)q0.x * sc + zp, (float)q0.y * sc + zp);
        bf.u[1] = pack_bf16((float)q0.z * sc + zp, (float)q0.w * sc + zp);
        bf.u[2] = pack_bf16((float)q1.x * sc + zp, (float)q1.y * sc + zp);
        bf.u[3] = pack_bf16((float)q1.z * sc + zp, (float)q1.w * sc + zp);
        a0.u[0] = pack_bf16(xa.x, xa.y);
        a0.u[1] = pack_bf16(xa.z, xa.w);
        a0.u[2] = pack_bf16(xb.x, xb.y);
        a0.u[3] = pack_bf16(xb.z, xb.w);
        a1.u[0] = pack_bf16(xc.x, xc.y);
        a1.u[1] = pack_bf16(xc.z, xc.w);
        a1.u[2] = pack_bf16(xd.x, xd.y);
        a1.u[3] = pack_bf16(xd.z, xd.w);

        acc0 = __builtin_amdgcn_mfma_f32_16x16x32_bf16(a0.v, bf.v, acc0, 0, 0, 0);
        acc1 = __builtin_amdgcn_mfma_f32_16x16x32_bf16(a1.v, bf.v, acc1, 0, 0, 0);
    }

    // epilogue: D col(lane&15)=n, row((lane>>4)*4+i)=m  (verified R0)
    const int ocol = nb * 64 + wv * 16 + lm;
    #pragma unroll
    for (int i = 0; i < 4; ++i) {
        int m0 = lq * 4 + i;
        atomicAdd(&out[(size_t)m0 * OUT_F + ocol], acc0[i]);
        atomicAdd(&out[(size_t)(16 + m0) * OUT_F + ocol], acc1[i]);
    }
}

extern "C" void kernel_launch(void* const* d_in, const int* in_sizes, int n_in,
                              void* d_out, int out_size, void* d_ws, size_t ws_size,
                              hipStream_t stream) {
    const float* x    = (const float*)d_in[0];   // [32, 4096] fp32
    const int*   wq   = (const int*)d_in[1];     // [11008, 4096] int32 (0..15)
    const float* sz   = (const float*)d_in[2];   // [128, 11008, 2] fp32
    const float* bias = (const float*)d_in[3];   // [11008] fp32
    float* out = (float*)d_out;                  // [32, 11008] fp32

    dim3 gi(OUT_F / 256, M_TOK);                 // 43 x 32
    init_out_kernel<<<gi, 256, 0, stream>>>(bias, out);

    dim3 gg((OUT_F / 64) * NSPLIT);              // 172 * 8 = 1376 blocks
    qgemm_kernel<<<gg, 256, 0, stream>>>(x, wq, sz, out);
}